// Round 1
// baseline (2568.527 us; speedup 1.0000x reference)
//
#include <hip/hip_runtime.h>
#include <math.h>

// PLRNN forward: B=256 batches, each one CU-resident workgroup running the
// T=1024 sequential recurrence. W2 (512x128 f32) lives in VGPRs (thread t owns
// row h=t); W1 (128x512) lives in LDS as bf16 pairs, XOR-swizzled in 16B slots
// so per-lane row reads are bank-conflict-free. 3 barriers/step.

#define NB 256
#define T  1024
#define DX 64
#define DZ 128
#define DH 512
#define DS 16

__device__ __forceinline__ unsigned int pk_bf16(float a, float b) {
  unsigned int ua = __float_as_uint(a);
  unsigned int ub = __float_as_uint(b);
  ua = (ua + 0x7fffu + ((ua >> 16) & 1u)) >> 16;   // RNE f32->bf16
  ub = (ub + 0x7fffu + ((ub >> 16) & 1u)) >> 16;
  return ua | (ub << 16);
}
__device__ __forceinline__ float bf_lo(unsigned int u) { return __uint_as_float(u << 16); }
__device__ __forceinline__ float bf_hi(unsigned int u) { return __uint_as_float(u & 0xffff0000u); }

__global__ __launch_bounds__(512, 2) void plrnn_kernel(
    const float* __restrict__ X, const float* __restrict__ S,
    const float* __restrict__ A, const float* __restrict__ W1,
    const float* __restrict__ W2, const float* __restrict__ h1,
    const float* __restrict__ h2, const float* __restrict__ C,
    float* __restrict__ out)
{
  __shared__ uint4 w1t[DZ * 64];        // 128 KiB: W1 bf16-packed, swizzled
  __shared__ float zf_lds[DZ];
  __shared__ float r_lds[DH];
  __shared__ float part_lds[DH];
  __shared__ float s_lds[2][DS];        // double-buffered input staging

  const int b   = blockIdx.x;
  const int tid = threadIdx.x;
  const int z   = tid & (DZ - 1);
  const int p   = tid >> 7;             // quarter of dh this thread covers in phase 2

  // ---- one-time: W2 row h=tid -> registers (f32). Strided but L1-friendly. ----
  float w2[DZ];
  {
    const float* w2row = W2 + ((size_t)b * DH + tid) * DZ;
    #pragma unroll
    for (int j = 0; j < DZ / 4; ++j) {
      const float4 v = *reinterpret_cast<const float4*>(w2row + 4 * j);
      w2[4*j+0] = v.x; w2[4*j+1] = v.y; w2[4*j+2] = v.z; w2[4*j+3] = v.w;
    }
  }
  const float h2reg = h2[(size_t)b * DH + tid];

  // ---- one-time: W1 -> LDS (bf16 pairs, XOR-swizzled 16B slot index) ----
  {
    const float* w1row = W1 + ((size_t)b * DZ + z) * DH + p * (DH / 4);
    const int swz = z & 63;
    #pragma unroll
    for (int j = 0; j < 16; ++j) {
      const float4 a0 = *reinterpret_cast<const float4*>(w1row + 8 * j);
      const float4 a1 = *reinterpret_cast<const float4*>(w1row + 8 * j + 4);
      uint4 w;
      w.x = pk_bf16(a0.x, a0.y);
      w.y = pk_bf16(a0.z, a0.w);
      w.z = pk_bf16(a1.x, a1.y);
      w.w = pk_bf16(a1.z, a1.w);
      w1t[z * 64 + ((p * 16 + j) ^ swz)] = w;
    }
  }

  // ---- one-time: per-z constants + state init (z0 = TF(0, X[:,0], alpha=1)) ----
  float Areg = 0.f, h1reg = 0.f;
  float Creg[DS];
  #pragma unroll
  for (int s = 0; s < DS; ++s) Creg[s] = 0.f;
  float zcur = 0.f, zfreg = 0.f, xcur = 0.f, scur = 0.f;

  if (tid < DZ) {
    Areg  = A[(size_t)b * DZ + z];
    h1reg = h1[(size_t)b * DZ + z];
    #pragma unroll
    for (int s = 0; s < DS / 4; ++s) {
      const float4 v = *reinterpret_cast<const float4*>(C + ((size_t)b * DZ + z) * DS + 4 * s);
      Creg[4*s+0] = v.x; Creg[4*s+1] = v.y; Creg[4*s+2] = v.z; Creg[4*s+3] = v.w;
    }
    if (z < DX) {
      const float x0 = X[((size_t)b * T) * DX + z];
      zcur = (x0 != x0) ? 0.f : x0;     // isnan -> head (=0)
      xcur = x0;                         // prefetched x for t=0
    }
  } else if (tid < DZ + DS) {
    scur = S[((size_t)b * T) * DS + (tid - DZ)];  // prefetched s for t=0
  }

  __syncthreads();

  for (int t = 0; t < T; ++t) {
    // ---- teacher forcing + s staging + prefetch of t+1 (latency hidden) ----
    if (tid < DZ) {
      float zfv;
      if (z < DX) {
        const float x = xcur;
        zfv = (x != x) ? zcur : (0.125f * x + 0.875f * zcur);
        const int tn = (t + 1 < T) ? (t + 1) : (T - 1);
        xcur = X[((size_t)b * T + tn) * DX + z];
      } else {
        zfv = zcur;
      }
      zf_lds[z] = zfv;
      zfreg = zfv;
    } else if (tid < DZ + DS) {
      s_lds[t & 1][tid - DZ] = scur;
      const int tn = (t + 1 < T) ? (t + 1) : (T - 1);
      scur = S[((size_t)b * T + tn) * DS + (tid - DZ)];
    }
    __syncthreads();

    // ---- phase 1: pre[h=tid] = h2 + sum_z W2[h,z]*zf[z] (zf broadcast reads) ----
    float pre = h2reg;
    #pragma unroll
    for (int j = 0; j < DZ / 4; ++j) {
      const float4 zf4 = *reinterpret_cast<const float4*>(&zf_lds[4 * j]);
      pre += w2[4*j+0] * zf4.x + w2[4*j+1] * zf4.y
           + w2[4*j+2] * zf4.z + w2[4*j+3] * zf4.w;
    }
    r_lds[tid] = fmaxf(pre, 0.f);
    __syncthreads();

    // ---- phase 2: partial[z,p] = sum_{h in p-quarter} W1[z,h]*r[h] ----
    {
      float partial = 0.f;
      const int rowbase = z * 64;
      const int swz = z & 63;
      #pragma unroll
      for (int j = 0; j < 16; ++j) {
        const uint4  w  = w1t[rowbase + ((p * 16 + j) ^ swz)];
        const float4 r0 = *reinterpret_cast<const float4*>(&r_lds[p * (DH/4) + 8*j]);
        const float4 r1 = *reinterpret_cast<const float4*>(&r_lds[p * (DH/4) + 8*j + 4]);
        partial += bf_lo(w.x) * r0.x + bf_hi(w.x) * r0.y
                 + bf_lo(w.y) * r0.z + bf_hi(w.y) * r0.w
                 + bf_lo(w.z) * r1.x + bf_hi(w.z) * r1.y
                 + bf_lo(w.w) * r1.z + bf_hi(w.w) * r1.w;
      }
      part_lds[tid] = partial;
    }
    __syncthreads();

    // ---- reduce 4 partials + state update (threads 0..127) ----
    if (tid < DZ) {
      const float u = part_lds[z] + part_lds[DZ + z]
                    + part_lds[2*DZ + z] + part_lds[3*DZ + z];
      float cs = 0.f;
      #pragma unroll
      for (int s = 0; s < DS; ++s) cs += Creg[s] * s_lds[t & 1][s];
      const float znew = Areg * zfreg + u + h1reg + cs;
      if (z < DX) out[((size_t)b * T + t) * DX + z] = znew;
      zcur = znew;
    }
    // no barrier needed here: next-step writers (zf_lds, s_lds other buffer)
    // are separated from this step's readers by the t+1 barriers.
  }
}

extern "C" void kernel_launch(void* const* d_in, const int* in_sizes, int n_in,
                              void* d_out, int out_size, void* d_ws, size_t ws_size,
                              hipStream_t stream) {
  const float* X  = (const float*)d_in[0];
  const float* S  = (const float*)d_in[1];
  const float* A  = (const float*)d_in[2];
  const float* W1 = (const float*)d_in[3];
  const float* W2 = (const float*)d_in[4];
  const float* h1 = (const float*)d_in[5];
  const float* h2 = (const float*)d_in[6];
  const float* C  = (const float*)d_in[7];
  float* out = (float*)d_out;
  plrnn_kernel<<<dim3(NB), dim3(512), 0, stream>>>(X, S, A, W1, W2, h1, h2, C, out);
}

// Round 2
// 1309.826 us; speedup vs baseline: 1.9610x; 1.9610x over previous
//
#include <hip/hip_runtime.h>
#include <math.h>

// PLRNN forward: 256 batches x 1024 sequential steps, 1 workgroup (512 thr,
// 8 waves) per batch, 1 per CU. All weights register-resident as packed f16
// pairs: W2 row h=tid (64 v2h), W1 row z / quarter p (64 v2h). Activations
// (zf, r) staged in LDS as f16, read wave-uniform as uint4, consumed by
// v_dot2_f32_f16 with f32 accumulation. State/update path stays f32.

#define NB 256
#define T  1024
#define DX 64
#define DZ 128
#define DH 512
#define DS 16

typedef _Float16 v2h __attribute__((ext_vector_type(2)));

__device__ __forceinline__ float dot2f(v2h a, v2h b, float c) {
#if __has_builtin(__builtin_amdgcn_fdot2)
  return __builtin_amdgcn_fdot2(a, b, c, false);
#else
  return c + (float)a.x * (float)b.x + (float)a.y * (float)b.y;
#endif
}

__device__ __forceinline__ v2h u2h(unsigned int u) {
  union { unsigned int u; v2h h; } cvt; cvt.u = u; return cvt.h;
}

__global__ __launch_bounds__(512, 2) void plrnn_kernel(
    const float* __restrict__ X, const float* __restrict__ S,
    const float* __restrict__ A, const float* __restrict__ W1,
    const float* __restrict__ W2, const float* __restrict__ h1,
    const float* __restrict__ h2, const float* __restrict__ C,
    float* __restrict__ out)
{
  __shared__ uint4 zfb[DZ / 8];        // 128 f16 = 256 B
  __shared__ uint4 rb[DH / 8];         // 512 f16 = 1 KiB
  __shared__ float part[4][DZ];        // 2 KiB
  __shared__ float s_lds[2][DS];       // double-buffered input staging

  const int b   = blockIdx.x;
  const int tid = threadIdx.x;
  const int z   = tid & (DZ - 1);
  const int p   = tid >> 7;            // quarter of dh in phase 2

  _Float16* zfh = (_Float16*)zfb;
  _Float16* rh  = (_Float16*)rb;

  // ---- one-time: W2 row h=tid -> 64 packed f16 pairs in VGPRs ----
  v2h w2[DZ / 2];
  {
    const float4* w2row = (const float4*)(W2 + ((size_t)b * DH + tid) * DZ);
    #pragma unroll
    for (int j = 0; j < DZ / 4; ++j) {
      const float4 v = w2row[j];
      v2h lo, hi;
      lo.x = (_Float16)v.x; lo.y = (_Float16)v.y;
      hi.x = (_Float16)v.z; hi.y = (_Float16)v.w;
      w2[2 * j] = lo; w2[2 * j + 1] = hi;
    }
  }
  const float h2reg = h2[(size_t)b * DH + tid];

  // ---- one-time: W1 row z, cols [p*128, p*128+128) -> 64 f16 pairs ----
  v2h w1r[DH / 8];
  {
    const float4* w1row = (const float4*)(W1 + ((size_t)b * DZ + z) * DH + p * (DH / 4));
    #pragma unroll
    for (int j = 0; j < DH / 16; ++j) {
      const float4 v = w1row[j];
      v2h lo, hi;
      lo.x = (_Float16)v.x; lo.y = (_Float16)v.y;
      hi.x = (_Float16)v.z; hi.y = (_Float16)v.w;
      w1r[2 * j] = lo; w1r[2 * j + 1] = hi;
    }
  }

  // ---- one-time: per-z constants + state init (z0 = TF(0, X[:,0], alpha=1)) ----
  float Areg = 0.f, h1reg = 0.f;
  float Creg[DS];
  #pragma unroll
  for (int s = 0; s < DS; ++s) Creg[s] = 0.f;
  float zcur = 0.f, zfreg = 0.f, xcur = 0.f, scur = 0.f;

  if (tid < DZ) {
    Areg  = A[(size_t)b * DZ + z];
    h1reg = h1[(size_t)b * DZ + z];
    #pragma unroll
    for (int s = 0; s < DS / 4; ++s) {
      const float4 v = *reinterpret_cast<const float4*>(C + ((size_t)b * DZ + z) * DS + 4 * s);
      Creg[4*s+0] = v.x; Creg[4*s+1] = v.y; Creg[4*s+2] = v.z; Creg[4*s+3] = v.w;
    }
    if (z < DX) {
      const float x0 = X[((size_t)b * T) * DX + z];
      zcur = (x0 != x0) ? 0.f : x0;    // isnan -> head (=0)
      xcur = x0;                        // prefetched x for t=0
    }
  } else if (tid < DZ + DS) {
    scur = S[((size_t)b * T) * DS + (tid - DZ)];
  }

  __syncthreads();

  for (int t = 0; t < T; ++t) {
    // ---- stage: teacher forcing (f32 state, f16 publish) + s + prefetch ----
    if (tid < DZ) {
      float zfv;
      if (z < DX) {
        const float x = xcur;
        zfv = (x != x) ? zcur : (0.125f * x + 0.875f * zcur);
        const int tn = (t + 1 < T) ? (t + 1) : (T - 1);
        xcur = X[((size_t)b * T + tn) * DX + z];
      } else {
        zfv = zcur;
      }
      zfh[z] = (_Float16)zfv;
      zfreg = zfv;
    } else if (tid < DZ + DS) {
      s_lds[t & 1][tid - DZ] = scur;
      const int tn = (t + 1 < T) ? (t + 1) : (T - 1);
      scur = S[((size_t)b * T + tn) * DS + (tid - DZ)];
    }
    __syncthreads();

    // ---- phase 1: pre[h=tid] = h2 + W2[h,:]·zf  (16 uniform b128 + 64 dot2) ----
    {
      float a0 = 0.f, a1 = 0.f, a2 = 0.f, a3 = 0.f;
      #pragma unroll
      for (int j = 0; j < DZ / 8; ++j) {
        const uint4 q = zfb[j];
        a0 = dot2f(w2[4*j+0], u2h(q.x), a0);
        a1 = dot2f(w2[4*j+1], u2h(q.y), a1);
        a2 = dot2f(w2[4*j+2], u2h(q.z), a2);
        a3 = dot2f(w2[4*j+3], u2h(q.w), a3);
      }
      const float pre = h2reg + ((a0 + a1) + (a2 + a3));
      rh[tid] = (_Float16)fmaxf(pre, 0.f);
    }
    __syncthreads();

    // ---- phase 2: part[p][z] = W1[z, p-quarter]·r  (16 uniform b128 + 64 dot2) ----
    {
      float b0 = 0.f, b1 = 0.f, b2 = 0.f, b3 = 0.f;
      const uint4* rq = rb + p * (DH / 32);
      #pragma unroll
      for (int j = 0; j < 16; ++j) {
        const uint4 q = rq[j];
        b0 = dot2f(w1r[4*j+0], u2h(q.x), b0);
        b1 = dot2f(w1r[4*j+1], u2h(q.y), b1);
        b2 = dot2f(w1r[4*j+2], u2h(q.z), b2);
        b3 = dot2f(w1r[4*j+3], u2h(q.w), b3);
      }
      part[p][z] = (b0 + b1) + (b2 + b3);
    }
    __syncthreads();

    // ---- reduce partials + f32 state update (threads 0..127) ----
    if (tid < DZ) {
      const float u = (part[0][z] + part[1][z]) + (part[2][z] + part[3][z]);
      float cs = 0.f;
      #pragma unroll
      for (int s = 0; s < DS; ++s) cs += Creg[s] * s_lds[t & 1][s];
      const float znew = Areg * zfreg + u + h1reg + cs;
      if (z < DX) out[((size_t)b * T + t) * DX + z] = znew;
      zcur = znew;
    }
    // next-step zf/s writes are separated from this step's readers by the
    // t+1 barriers; s is double-buffered for the update-phase overlap.
  }
}

extern "C" void kernel_launch(void* const* d_in, const int* in_sizes, int n_in,
                              void* d_out, int out_size, void* d_ws, size_t ws_size,
                              hipStream_t stream) {
  const float* X  = (const float*)d_in[0];
  const float* S  = (const float*)d_in[1];
  const float* A  = (const float*)d_in[2];
  const float* W1 = (const float*)d_in[3];
  const float* W2 = (const float*)d_in[4];
  const float* h1 = (const float*)d_in[5];
  const float* h2 = (const float*)d_in[6];
  const float* C  = (const float*)d_in[7];
  float* out = (float*)d_out;
  plrnn_kernel<<<dim3(NB), dim3(512), 0, stream>>>(X, S, A, W1, W2, h1, h2, C, out);
}

// Round 3
// 1266.817 us; speedup vs baseline: 2.0275x; 1.0340x over previous
//
#include <hip/hip_runtime.h>
#include <math.h>

// PLRNN forward via MFMA matvec: 256 batches x 1024 sequential steps,
// 1 workgroup (512 thr, 8 waves) per batch, 1 per CU.
// Weights live as resident f16 MFMA A-fragments (zero per-step weight traffic):
//   phase 1: pre = W2·zf   (M=512 rows split by wave: wave w owns rows 64w..64w+64,
//            4 M-tiles x 4 K-tiles of 16x16x32)
//   phase 2: u_partial = W1[:, 64w..64w+64)·r[64w..64w+64)  (K-split by wave:
//            8 M-tiles x 2 K-tiles), r produced by the SAME wave in phase 1 ->
//            no barrier between phases, only a wave-local LDS bounce.
// B-operand (activations) is broadcast per 16-lane group from tiny LDS buffers.
// Accumulation f32; state update fully f32. 2 barriers/step.

#define NB 256
#define T  1024
#define DX 64
#define DZ 128
#define DH 512
#define DS 16

typedef _Float16 half8 __attribute__((ext_vector_type(8)));
typedef _Float16 v2h   __attribute__((ext_vector_type(2)));
typedef float    f32x4 __attribute__((ext_vector_type(4)));

__device__ __forceinline__ half8 cvt8(const float* __restrict__ src) {
  const float4 a = *reinterpret_cast<const float4*>(src);
  const float4 c = *reinterpret_cast<const float4*>(src + 4);
  half8 h;
  h[0] = (_Float16)a.x; h[1] = (_Float16)a.y; h[2] = (_Float16)a.z; h[3] = (_Float16)a.w;
  h[4] = (_Float16)c.x; h[5] = (_Float16)c.y; h[6] = (_Float16)c.z; h[7] = (_Float16)c.w;
  return h;
}

__global__ __launch_bounds__(512, 2) void plrnn_kernel(
    const float* __restrict__ X, const float* __restrict__ S,
    const float* __restrict__ A, const float* __restrict__ W1,
    const float* __restrict__ W2, const float* __restrict__ h1,
    const float* __restrict__ h2, const float* __restrict__ C,
    float* __restrict__ out)
{
  __shared__ _Float16 zf_h[DZ];        // 256 B: zf broadcast (f16)
  __shared__ _Float16 r_h[8][64];      // 1 KiB: per-wave r bounce
  __shared__ float    part[8][DZ];     // 4 KiB: phase-2 K-partials
  __shared__ float    s_lds[2][DS];    // double-buffered s_t

  const int b   = blockIdx.x;
  const int tid = threadIdx.x;
  const int w   = tid >> 6;            // wave 0..7
  const int l   = tid & 63;
  const int g   = l >> 4;              // 16-lane group 0..3 (K-slice group)
  const int r15 = l & 15;              // row-in-tile (A) / col (B,D)

  // ---- one-time: W2 A-fragments (wave w: rows 64w+16mt+r15, k=32kt+8g+e) ----
  half8 w2f[4][4];
  #pragma unroll
  for (int mt = 0; mt < 4; ++mt)
    #pragma unroll
    for (int kt = 0; kt < 4; ++kt)
      w2f[mt][kt] = cvt8(W2 + ((size_t)b * DH + 64 * w + 16 * mt + r15) * DZ + 32 * kt + 8 * g);

  // ---- one-time: W1 A-fragments (rows z=16mt+r15, k=h=64w+32kt+8g+e) ----
  half8 w1f[8][2];
  #pragma unroll
  for (int mt = 0; mt < 8; ++mt)
    #pragma unroll
    for (int kt = 0; kt < 2; ++kt)
      w1f[mt][kt] = cvt8(W1 + ((size_t)b * DZ + 16 * mt + r15) * DH + 64 * w + 32 * kt + 8 * g);

  // ---- one-time: h2 as acc-init (D: row = 4g + reg) ----
  f32x4 h2v[4];
  #pragma unroll
  for (int mt = 0; mt < 4; ++mt)
    h2v[mt] = *reinterpret_cast<const f32x4*>(h2 + (size_t)b * DH + 64 * w + 16 * mt + 4 * g);

  // ---- one-time: update-thread constants + state init ----
  float Areg = 0.f, h1reg = 0.f, zfreg = 0.f, xcur = 0.f, scur = 0.f;
  float Creg[DS];
  #pragma unroll
  for (int s = 0; s < DS; ++s) Creg[s] = 0.f;

  if (tid < DZ) {
    Areg  = A[(size_t)b * DZ + tid];
    h1reg = h1[(size_t)b * DZ + tid];
    #pragma unroll
    for (int s = 0; s < DS / 4; ++s) {
      const float4 v = *reinterpret_cast<const float4*>(C + ((size_t)b * DZ + tid) * DS + 4 * s);
      Creg[4*s+0] = v.x; Creg[4*s+1] = v.y; Creg[4*s+2] = v.z; Creg[4*s+3] = v.w;
    }
    float zfv = 0.f;
    if (tid < DX) {
      const float x = X[((size_t)b * T) * DX + tid];
      const float z0 = (x != x) ? 0.f : x;                 // TF(0, X0, alpha=1)
      zfv = (x != x) ? z0 : (0.125f * x + 0.875f * z0);    // TF for t=0
      xcur = X[((size_t)b * T + 1) * DX + tid];            // prefetch X[1]
    }
    zf_h[tid] = (_Float16)zfv;
    zfreg = zfv;
  } else if (tid < DZ + DS) {
    s_lds[0][tid - DZ] = S[((size_t)b * T) * DS + (tid - DZ)];
    scur = S[((size_t)b * T + 1) * DS + (tid - DZ)];       // prefetch S[1]
  }
  __syncthreads();

  const f32x4 zero4 = {0.f, 0.f, 0.f, 0.f};

  for (int t = 0; t < T; ++t) {
    // ---- phase 1: pre = h2 + W2·zf (16 MFMA), B = zf bcast per 16-lane group ----
    half8 bz[4];
    #pragma unroll
    for (int kt = 0; kt < 4; ++kt)
      bz[kt] = *reinterpret_cast<const half8*>(zf_h + 32 * kt + 8 * g);

    f32x4 acc1[4];
    #pragma unroll
    for (int mt = 0; mt < 4; ++mt) acc1[mt] = h2v[mt];
    #pragma unroll
    for (int kt = 0; kt < 4; ++kt)
      #pragma unroll
      for (int mt = 0; mt < 4; ++mt)
        acc1[mt] = __builtin_amdgcn_mfma_f32_16x16x32_f16(w2f[mt][kt], bz[kt], acc1[mt], 0, 0, 0);

    // ---- ReLU + f16 + wave-local bounce (col 0 lanes hold rows 4g+reg) ----
    if (r15 == 0) {
      #pragma unroll
      for (int mt = 0; mt < 4; ++mt) {
        v2h p0, p1;
        p0.x = (_Float16)fmaxf(acc1[mt][0], 0.f);
        p0.y = (_Float16)fmaxf(acc1[mt][1], 0.f);
        p1.x = (_Float16)fmaxf(acc1[mt][2], 0.f);
        p1.y = (_Float16)fmaxf(acc1[mt][3], 0.f);
        *reinterpret_cast<v2h*>(&r_h[w][16 * mt + 4 * g])     = p0;
        *reinterpret_cast<v2h*>(&r_h[w][16 * mt + 4 * g + 2]) = p1;
      }
    }

    // ---- phase 2: partial u over k-range [64w,64w+64) (16 MFMA), same wave ----
    half8 br[2];
    #pragma unroll
    for (int kt = 0; kt < 2; ++kt)
      br[kt] = *reinterpret_cast<const half8*>(&r_h[w][32 * kt + 8 * g]);

    f32x4 acc2[8];
    #pragma unroll
    for (int mt = 0; mt < 8; ++mt) acc2[mt] = zero4;
    #pragma unroll
    for (int kt = 0; kt < 2; ++kt)
      #pragma unroll
      for (int mt = 0; mt < 8; ++mt)
        acc2[mt] = __builtin_amdgcn_mfma_f32_16x16x32_f16(w1f[mt][kt], br[kt], acc2[mt], 0, 0, 0);

    if (r15 == 0) {
      #pragma unroll
      for (int mt = 0; mt < 8; ++mt)
        *reinterpret_cast<f32x4*>(&part[w][16 * mt + 4 * g]) = acc2[mt];
    }
    __syncthreads();   // B1: partials + s staging visible to update threads

    // ---- update (threads 0..127): reduce 8 partials + f32 state update + TF ----
    if (tid < DZ) {
      float u = 0.f;
      #pragma unroll
      for (int ww = 0; ww < 8; ++ww) u += part[ww][tid];
      float cs = 0.f;
      #pragma unroll
      for (int s = 0; s < DS; ++s) cs += Creg[s] * s_lds[t & 1][s];
      const float znew = Areg * zfreg + u + h1reg + cs;
      if (tid < DX) out[((size_t)b * T + t) * DX + tid] = znew;

      // teacher forcing for step t+1 (xcur = X[t+1], prefetched)
      const float x = xcur;
      float zfv = znew;
      if (tid < DX) {
        zfv = (x != x) ? znew : (0.125f * x + 0.875f * znew);
        const int tn = (t + 2 < T) ? (t + 2) : (T - 1);
        xcur = X[((size_t)b * T + tn) * DX + tid];
      }
      zf_h[tid] = (_Float16)zfv;
      zfreg = zfv;
    } else if (tid < DZ + DS) {
      s_lds[(t + 1) & 1][tid - DZ] = scur;
      const int tn = (t + 2 < T) ? (t + 2) : (T - 1);
      scur = S[((size_t)b * T + tn) * DS + (tid - DZ)];
    }
    __syncthreads();   // B2: zf(t+1) visible to all waves
  }
}

extern "C" void kernel_launch(void* const* d_in, const int* in_sizes, int n_in,
                              void* d_out, int out_size, void* d_ws, size_t ws_size,
                              hipStream_t stream) {
  const float* X  = (const float*)d_in[0];
  const float* S  = (const float*)d_in[1];
  const float* A  = (const float*)d_in[2];
  const float* W1 = (const float*)d_in[3];
  const float* W2 = (const float*)d_in[4];
  const float* h1 = (const float*)d_in[5];
  const float* h2 = (const float*)d_in[6];
  const float* C  = (const float*)d_in[7];
  float* out = (float*)d_out;
  plrnn_kernel<<<dim3(NB), dim3(512), 0, stream>>>(X, S, A, W1, W2, h1, h2, C, out);
}

// Round 4
// 1196.796 us; speedup vs baseline: 2.1462x; 1.0585x over previous
//
#include <hip/hip_runtime.h>
#include <math.h>

// PLRNN forward via MFMA matvec, chunked LDS I/O staging.
// 256 batches x 1024 steps, 1 WG (512 thr, 8 waves) per batch, 1 per CU.
// Weights resident as f16 MFMA A-fragments. Per step:
//   phase 1 (M-split): wave w computes pre rows [64w,64w+64) = 4x4 MFMA 16x16x32
//   phase 2 (K-split): wave w computes partial u over k=[64w,64w+64) = 8x2 MFMA
//   B1; update on threads 0..127 (reduce partials, C.s, A*zf, TF); B2.
// X/S staged into LDS per 128-step chunk; out accumulated in LDS and flushed
// per chunk -> steady-state steps have NO global ops, so the compiler's
// s_waitcnt vmcnt(0) before each s_barrier is free.

#define NB 256
#define T  1024
#define DX 64
#define DZ 128
#define DH 512
#define DS 16
#define CHUNK 128

typedef _Float16 half8 __attribute__((ext_vector_type(8)));
typedef _Float16 v4h   __attribute__((ext_vector_type(4)));
typedef float    f32x4 __attribute__((ext_vector_type(4)));

__device__ __forceinline__ half8 cvt8(const float* __restrict__ src) {
  const float4 a = *reinterpret_cast<const float4*>(src);
  const float4 c = *reinterpret_cast<const float4*>(src + 4);
  half8 h;
  h[0] = (_Float16)a.x; h[1] = (_Float16)a.y; h[2] = (_Float16)a.z; h[3] = (_Float16)a.w;
  h[4] = (_Float16)c.x; h[5] = (_Float16)c.y; h[6] = (_Float16)c.z; h[7] = (_Float16)c.w;
  return h;
}

__global__ __launch_bounds__(512, 2) void plrnn_kernel(
    const float* __restrict__ X, const float* __restrict__ S,
    const float* __restrict__ A, const float* __restrict__ W1,
    const float* __restrict__ W2, const float* __restrict__ h1,
    const float* __restrict__ h2, const float* __restrict__ C,
    float* __restrict__ out)
{
  __shared__ __align__(16) _Float16 zf_h[DZ];          // 256 B
  __shared__ __align__(16) _Float16 r_h[8][64];        // 1 KiB
  __shared__ __align__(16) float    part[8][DZ];       // 4 KiB
  __shared__ __align__(16) float    Xc[CHUNK][DX];     // 32 KiB: X[t+1..t+128]
  __shared__ __align__(16) float    Sc[CHUNK][DS];     // 8 KiB:  S[t..t+127]
  __shared__ __align__(16) float    outc[CHUNK][DX];   // 32 KiB

  const int b   = blockIdx.x;
  const int tid = threadIdx.x;
  const int w   = tid >> 6;            // wave 0..7
  const int l   = tid & 63;
  const int g   = l >> 4;              // 16-lane group (K-slice group)
  const int r15 = l & 15;              // row-in-tile (A) / col (B,D)

  // ---- one-time: stage chunk 0 (issue early; X rows 1..128, S rows 0..127) ----
  {
    #pragma unroll
    for (int k = 0; k < 4; ++k) {
      const int flat = k * 2048 + tid * 4;
      int srow = 1 + (flat >> 6);
      if (srow > T - 1) srow = T - 1;
      const float4 v = *reinterpret_cast<const float4*>(X + ((size_t)b * T + srow) * DX + (flat & 63));
      *reinterpret_cast<float4*>(&((float*)Xc)[flat]) = v;
    }
    const int flat = tid * 4;
    const float4 v = *reinterpret_cast<const float4*>(S + ((size_t)b * T) * DS + flat);
    *reinterpret_cast<float4*>(&((float*)Sc)[flat]) = v;
  }

  // ---- one-time: W2 A-fragments (wave w: rows 64w+16mt+r15, k=32kt+8g+e) ----
  half8 w2f[4][4];
  #pragma unroll
  for (int mt = 0; mt < 4; ++mt)
    #pragma unroll
    for (int kt = 0; kt < 4; ++kt)
      w2f[mt][kt] = cvt8(W2 + ((size_t)b * DH + 64 * w + 16 * mt + r15) * DZ + 32 * kt + 8 * g);

  // ---- one-time: W1 A-fragments (rows z=16mt+r15, k=h=64w+32kt+8g+e) ----
  half8 w1f[8][2];
  #pragma unroll
  for (int mt = 0; mt < 8; ++mt)
    #pragma unroll
    for (int kt = 0; kt < 2; ++kt)
      w1f[mt][kt] = cvt8(W1 + ((size_t)b * DZ + 16 * mt + r15) * DH + 64 * w + 32 * kt + 8 * g);

  // ---- one-time: h2 as acc-init (D row = 4g + reg) ----
  f32x4 h2v[4];
  #pragma unroll
  for (int mt = 0; mt < 4; ++mt)
    h2v[mt] = *reinterpret_cast<const f32x4*>(h2 + (size_t)b * DH + 64 * w + 16 * mt + 4 * g);

  // ---- one-time: update-thread constants + state init ----
  float Areg = 0.f, h1reg = 0.f, zfreg = 0.f;
  float Creg[DS];
  #pragma unroll
  for (int s = 0; s < DS; ++s) Creg[s] = 0.f;

  if (tid < DZ) {
    Areg  = A[(size_t)b * DZ + tid];
    h1reg = h1[(size_t)b * DZ + tid];
    #pragma unroll
    for (int s = 0; s < DS / 4; ++s) {
      const float4 v = *reinterpret_cast<const float4*>(C + ((size_t)b * DZ + tid) * DS + 4 * s);
      Creg[4*s+0] = v.x; Creg[4*s+1] = v.y; Creg[4*s+2] = v.z; Creg[4*s+3] = v.w;
    }
    float zfv = 0.f;
    if (tid < DX) {
      const float x = X[((size_t)b * T) * DX + tid];
      const float z0 = (x != x) ? 0.f : x;                 // TF(0, X0, alpha=1)
      zfv = (x != x) ? z0 : (0.125f * x + 0.875f * z0);    // TF for step 0
    }
    zf_h[tid] = (_Float16)zfv;
    zfreg = zfv;
  }
  __syncthreads();

  const f32x4 zero4 = {0.f, 0.f, 0.f, 0.f};

  for (int t = 0; t < T; ++t) {
    // ---- chunk boundary: flush finished out-chunk, stage next X/S chunk ----
    if ((t & (CHUNK - 1)) == 0 && t) {
      const int c0 = t - CHUNK;
      #pragma unroll
      for (int k = 0; k < 4; ++k) {
        const int flat = k * 2048 + tid * 4;
        const float4 v = *reinterpret_cast<const float4*>(&((float*)outc)[flat]);
        *reinterpret_cast<float4*>(out + ((size_t)b * T + c0) * DX + flat) = v;
      }
      #pragma unroll
      for (int k = 0; k < 4; ++k) {
        const int flat = k * 2048 + tid * 4;
        int srow = t + 1 + (flat >> 6);
        if (srow > T - 1) srow = T - 1;
        const float4 v = *reinterpret_cast<const float4*>(X + ((size_t)b * T + srow) * DX + (flat & 63));
        *reinterpret_cast<float4*>(&((float*)Xc)[flat]) = v;
      }
      const int flat = tid * 4;
      const float4 v = *reinterpret_cast<const float4*>(S + ((size_t)b * T + t) * DS + flat);
      *reinterpret_cast<float4*>(&((float*)Sc)[flat]) = v;
      __syncthreads();
    }
    const int tc = t & (CHUNK - 1);

    // ---- phase 1: pre = h2 + W2·zf (16 MFMA) ----
    half8 bz[4];
    #pragma unroll
    for (int kt = 0; kt < 4; ++kt)
      bz[kt] = *reinterpret_cast<const half8*>(zf_h + 32 * kt + 8 * g);

    f32x4 acc1[4];
    #pragma unroll
    for (int mt = 0; mt < 4; ++mt) acc1[mt] = h2v[mt];
    #pragma unroll
    for (int kt = 0; kt < 4; ++kt)
      #pragma unroll
      for (int mt = 0; mt < 4; ++mt)
        acc1[mt] = __builtin_amdgcn_mfma_f32_16x16x32_f16(w2f[mt][kt], bz[kt], acc1[mt], 0, 0, 0);

    // ---- ReLU + f16 + wave-local bounce (4 packed b64 writes per wave) ----
    if (r15 == 0) {
      #pragma unroll
      for (int mt = 0; mt < 4; ++mt) {
        v4h p;
        p.x = (_Float16)fmaxf(acc1[mt][0], 0.f);
        p.y = (_Float16)fmaxf(acc1[mt][1], 0.f);
        p.z = (_Float16)fmaxf(acc1[mt][2], 0.f);
        p.w = (_Float16)fmaxf(acc1[mt][3], 0.f);
        *reinterpret_cast<v4h*>(&r_h[w][16 * mt + 4 * g]) = p;
      }
    }

    // ---- phase 2: partial u over k=[64w,64w+64) (16 MFMA, same wave) ----
    half8 br[2];
    #pragma unroll
    for (int kt = 0; kt < 2; ++kt)
      br[kt] = *reinterpret_cast<const half8*>(&r_h[w][32 * kt + 8 * g]);

    f32x4 acc2[8];
    #pragma unroll
    for (int mt = 0; mt < 8; ++mt) acc2[mt] = zero4;
    #pragma unroll
    for (int kt = 0; kt < 2; ++kt)
      #pragma unroll
      for (int mt = 0; mt < 8; ++mt)
        acc2[mt] = __builtin_amdgcn_mfma_f32_16x16x32_f16(w1f[mt][kt], br[kt], acc2[mt], 0, 0, 0);

    if (r15 == 0) {
      #pragma unroll
      for (int mt = 0; mt < 8; ++mt)
        *reinterpret_cast<f32x4*>(&part[w][16 * mt + 4 * g]) = acc2[mt];
    }
    __syncthreads();   // B1: partials visible to update threads

    // ---- update (threads 0..127), all I/O through LDS ----
    if (tid < DZ) {
      float u = 0.f;
      #pragma unroll
      for (int ww = 0; ww < 8; ++ww) u += part[ww][tid];
      float cs = 0.f;
      #pragma unroll
      for (int s = 0; s < DS / 4; ++s) {
        const float4 sv = *reinterpret_cast<const float4*>(&Sc[tc][4 * s]);
        cs += Creg[4*s+0] * sv.x + Creg[4*s+1] * sv.y
            + Creg[4*s+2] * sv.z + Creg[4*s+3] * sv.w;
      }
      const float znew = Areg * zfreg + u + h1reg + cs;

      float zfv = znew;
      if (tid < DX) {
        outc[tc][tid] = znew;
        const float x = Xc[tc][tid];                      // X[t+1]
        zfv = (x != x) ? znew : (0.125f * x + 0.875f * znew);
      }
      zf_h[tid] = (_Float16)zfv;
      zfreg = zfv;
    }
    __syncthreads();   // B2: zf(t+1) visible to all waves
  }

  // ---- final flush (chunk 7) ----
  {
    const int c0 = T - CHUNK;
    #pragma unroll
    for (int k = 0; k < 4; ++k) {
      const int flat = k * 2048 + tid * 4;
      const float4 v = *reinterpret_cast<const float4*>(&((float*)outc)[flat]);
      *reinterpret_cast<float4*>(out + ((size_t)b * T + c0) * DX + flat) = v;
    }
  }
}

extern "C" void kernel_launch(void* const* d_in, const int* in_sizes, int n_in,
                              void* d_out, int out_size, void* d_ws, size_t ws_size,
                              hipStream_t stream) {
  const float* X  = (const float*)d_in[0];
  const float* S  = (const float*)d_in[1];
  const float* A  = (const float*)d_in[2];
  const float* W1 = (const float*)d_in[3];
  const float* W2 = (const float*)d_in[4];
  const float* h1 = (const float*)d_in[5];
  const float* h2 = (const float*)d_in[6];
  const float* C  = (const float*)d_in[7];
  float* out = (float*)d_out;
  plrnn_kernel<<<dim3(NB), dim3(512), 0, stream>>>(X, S, A, W1, W2, h1, h2, C, out);
}

// Round 5
// 1030.165 us; speedup vs baseline: 2.4933x; 1.1618x over previous
//
#include <hip/hip_runtime.h>
#include <math.h>

// PLRNN forward via MFMA matvec, fully distributed update.
// 256 batches x 1024 steps, 1 WG (512 thr, 8 waves) per batch, 1 per CU.
// Weights resident as f16 MFMA A-fragments. Per step:
//   phase 1 (M-split): wave w computes pre rows [64w,64w+64): 4x4 MFMA 16x16x32,
//           ReLU -> f16 -> bounce to rt[0..511]; s_t -> rt[512..527].  B0.
//   phase 2 (M-split): wave w computes u rows [16w,16w+16) with K=544 extended
//           operand W~1 = [W1 | C | h1col | 0] vs r~ = [r | s~ | 1,0...]:
//           17 MFMA. C.s and h1 folded into the matrix pipe.
//   update: distributed to each wave's D-lanes (r15==0): znew = A*zfcur + u,
//           teacher-force with Xc, write zf_h + outc. B2.
// X/S/out staged in LDS per 128-step chunk -> no global ops in steady state.

#define NB 256
#define T  1024
#define DX 64
#define DZ 128
#define DH 512
#define DS 16
#define CHUNK 128

typedef _Float16 half8 __attribute__((ext_vector_type(8)));
typedef _Float16 v4h   __attribute__((ext_vector_type(4)));
typedef float    f32x4 __attribute__((ext_vector_type(4)));

__device__ __forceinline__ half8 cvt8(const float* __restrict__ src) {
  const float4 a = *reinterpret_cast<const float4*>(src);
  const float4 c = *reinterpret_cast<const float4*>(src + 4);
  half8 h;
  h[0] = (_Float16)a.x; h[1] = (_Float16)a.y; h[2] = (_Float16)a.z; h[3] = (_Float16)a.w;
  h[4] = (_Float16)c.x; h[5] = (_Float16)c.y; h[6] = (_Float16)c.z; h[7] = (_Float16)c.w;
  return h;
}

__global__ __launch_bounds__(512, 2) void plrnn_kernel(
    const float* __restrict__ X, const float* __restrict__ S,
    const float* __restrict__ A, const float* __restrict__ W1,
    const float* __restrict__ W2, const float* __restrict__ h1,
    const float* __restrict__ h2, const float* __restrict__ C,
    float* __restrict__ out)
{
  __shared__ __align__(16) _Float16 zf_h[DZ];          // 256 B
  __shared__ __align__(16) _Float16 rt[544];           // r(512)+s~(16)+[1,0..](16)
  __shared__ __align__(16) float    Xc[CHUNK][DX];     // 32 KiB: X[t+1..t+128]
  __shared__ __align__(16) float    Sc[CHUNK][DS];     // 8 KiB:  S[t..t+127]
  __shared__ __align__(16) float    outc[CHUNK][DX];   // 32 KiB

  const int b   = blockIdx.x;
  const int tid = threadIdx.x;
  const int w   = tid >> 6;            // wave 0..7
  const int l   = tid & 63;
  const int g   = l >> 4;              // 16-lane group (K-slice group)
  const int r15 = l & 15;              // A row-in-tile / D col

  // ---- one-time: stage chunk 0 (X rows 1..128 clamped, S rows 0..127) ----
  {
    #pragma unroll
    for (int k = 0; k < 4; ++k) {
      const int flat = k * 2048 + tid * 4;
      int srow = 1 + (flat >> 6);
      if (srow > T - 1) srow = T - 1;
      const float4 v = *reinterpret_cast<const float4*>(X + ((size_t)b * T + srow) * DX + (flat & 63));
      *reinterpret_cast<float4*>(&((float*)Xc)[flat]) = v;
    }
    const int flat = tid * 4;
    const float4 v = *reinterpret_cast<const float4*>(S + ((size_t)b * T) * DS + flat);
    *reinterpret_cast<float4*>(&((float*)Sc)[flat]) = v;
  }

  // ---- one-time: rt constant tail [528..543] = [1, 0...0] ----
  if (tid < 16) rt[528 + tid] = (tid == 0) ? (_Float16)1.0f : (_Float16)0.0f;

  // ---- one-time: W2 A-fragments (wave w: rows 64w+16mt+r15, k=32kt+8g+e) ----
  half8 w2f[4][4];
  #pragma unroll
  for (int mt = 0; mt < 4; ++mt)
    #pragma unroll
    for (int kt = 0; kt < 4; ++kt)
      w2f[mt][kt] = cvt8(W2 + ((size_t)b * DH + 64 * w + 16 * mt + r15) * DZ + 32 * kt + 8 * g);

  // ---- one-time: W~1 A-fragments (wave w: row z=16w+r15, k=32kt+8g+e) ----
  half8 w1f[16];
  #pragma unroll
  for (int kt = 0; kt < 16; ++kt)
    w1f[kt] = cvt8(W1 + ((size_t)b * DZ + 16 * w + r15) * DH + 32 * kt + 8 * g);
  // tail K-tile (kt=16): k=512..543 -> [C cols | h1 col | zeros]
  half8 w1ft;
  #pragma unroll
  for (int e = 0; e < 8; ++e) w1ft[e] = (_Float16)0.0f;
  if (g == 0)      w1ft = cvt8(C + ((size_t)b * DZ + 16 * w + r15) * DS + 0);
  else if (g == 1) w1ft = cvt8(C + ((size_t)b * DZ + 16 * w + r15) * DS + 8);
  else if (g == 2) w1ft[0] = (_Float16)h1[(size_t)b * DZ + 16 * w + r15];

  // ---- one-time: h2 as acc-init (D rows 4g+j) ----
  f32x4 h2v[4];
  #pragma unroll
  for (int mt = 0; mt < 4; ++mt)
    h2v[mt] = *reinterpret_cast<const f32x4*>(h2 + (size_t)b * DH + 64 * w + 16 * mt + 4 * g);

  // ---- one-time: D-lane constants + state init (zf(0) = TF(z0, X0, 1/8)) ----
  f32x4 Areg = {0.f, 0.f, 0.f, 0.f};
  f32x4 zfcur = {0.f, 0.f, 0.f, 0.f};
  if (r15 == 0) {
    Areg = *reinterpret_cast<const f32x4*>(A + (size_t)b * DZ + 16 * w + 4 * g);
    if (w < 4) {
      const f32x4 x0 = *reinterpret_cast<const f32x4*>(X + ((size_t)b * T) * DX + 16 * w + 4 * g);
      #pragma unroll
      for (int j = 0; j < 4; ++j) {
        const float x = x0[j];
        const float z0 = (x != x) ? 0.f : x;
        zfcur[j] = (x != x) ? z0 : (0.125f * x + 0.875f * z0);
      }
    }
    v4h zp;
    #pragma unroll
    for (int j = 0; j < 4; ++j) zp[j] = (_Float16)zfcur[j];
    *reinterpret_cast<v4h*>(&zf_h[16 * w + 4 * g]) = zp;
  }
  __syncthreads();

  const f32x4 zero4 = {0.f, 0.f, 0.f, 0.f};

  for (int t = 0; t < T; ++t) {
    // ---- chunk boundary: flush out-chunk, stage next X/S chunk ----
    if ((t & (CHUNK - 1)) == 0 && t) {
      const int c0 = t - CHUNK;
      #pragma unroll
      for (int k = 0; k < 4; ++k) {
        const int flat = k * 2048 + tid * 4;
        const float4 v = *reinterpret_cast<const float4*>(&((float*)outc)[flat]);
        *reinterpret_cast<float4*>(out + ((size_t)b * T + c0) * DX + flat) = v;
      }
      #pragma unroll
      for (int k = 0; k < 4; ++k) {
        const int flat = k * 2048 + tid * 4;
        int srow = t + 1 + (flat >> 6);
        if (srow > T - 1) srow = T - 1;
        const float4 v = *reinterpret_cast<const float4*>(X + ((size_t)b * T + srow) * DX + (flat & 63));
        *reinterpret_cast<float4*>(&((float*)Xc)[flat]) = v;
      }
      const int flat = tid * 4;
      const float4 v = *reinterpret_cast<const float4*>(S + ((size_t)b * T + t) * DS + flat);
      *reinterpret_cast<float4*>(&((float*)Sc)[flat]) = v;
      __syncthreads();
    }
    const int tc = t & (CHUNK - 1);

    // ---- phase 1: pre = h2 + W2·zf (16 MFMA) ----
    half8 bz[4];
    #pragma unroll
    for (int kt = 0; kt < 4; ++kt)
      bz[kt] = *reinterpret_cast<const half8*>(zf_h + 32 * kt + 8 * g);

    f32x4 acc1[4];
    #pragma unroll
    for (int mt = 0; mt < 4; ++mt) acc1[mt] = h2v[mt];
    #pragma unroll
    for (int kt = 0; kt < 4; ++kt)
      #pragma unroll
      for (int mt = 0; mt < 4; ++mt)
        acc1[mt] = __builtin_amdgcn_mfma_f32_16x16x32_f16(w2f[mt][kt], bz[kt], acc1[mt], 0, 0, 0);

    // ---- ReLU + f16 bounce to rt[64w..64w+64) ----
    if (r15 == 0) {
      #pragma unroll
      for (int mt = 0; mt < 4; ++mt) {
        v4h p;
        p.x = (_Float16)fmaxf(acc1[mt][0], 0.f);
        p.y = (_Float16)fmaxf(acc1[mt][1], 0.f);
        p.z = (_Float16)fmaxf(acc1[mt][2], 0.f);
        p.w = (_Float16)fmaxf(acc1[mt][3], 0.f);
        *reinterpret_cast<v4h*>(&rt[64 * w + 16 * mt + 4 * g]) = p;
      }
    }
    // ---- s~ for this step ----
    if (tid < 16) rt[512 + tid] = (_Float16)Sc[tc][tid];
    __syncthreads();   // B0: rt complete

    // ---- phase 2: u rows [16w,16w+16) over K=544 (17 MFMA, 4 acc chains) ----
    f32x4 acc2[4];
    #pragma unroll
    for (int i = 0; i < 4; ++i) acc2[i] = zero4;
    #pragma unroll
    for (int kt = 0; kt < 16; ++kt) {
      const half8 br = *reinterpret_cast<const half8*>(rt + 32 * kt + 8 * g);
      acc2[kt & 3] = __builtin_amdgcn_mfma_f32_16x16x32_f16(w1f[kt], br, acc2[kt & 3], 0, 0, 0);
    }
    {
      const half8 br = *reinterpret_cast<const half8*>(rt + 512 + 8 * g);
      acc2[0] = __builtin_amdgcn_mfma_f32_16x16x32_f16(w1ft, br, acc2[0], 0, 0, 0);
    }

    // ---- distributed update on D-lanes: znew = A*zfcur + u; TF; publish ----
    if (r15 == 0) {
      const f32x4 u = (acc2[0] + acc2[1]) + (acc2[2] + acc2[3]);
      f32x4 zn, zfn;
      #pragma unroll
      for (int j = 0; j < 4; ++j) zn[j] = Areg[j] * zfcur[j] + u[j];
      zfn = zn;
      if (w < 4) {
        *reinterpret_cast<f32x4*>(&outc[tc][16 * w + 4 * g]) = zn;
        const f32x4 xv = *reinterpret_cast<const f32x4*>(&Xc[tc][16 * w + 4 * g]);
        #pragma unroll
        for (int j = 0; j < 4; ++j) {
          const float x = xv[j];
          zfn[j] = (x != x) ? zn[j] : (0.125f * x + 0.875f * zn[j]);
        }
      }
      zfcur = zfn;
      v4h zp;
      #pragma unroll
      for (int j = 0; j < 4; ++j) zp[j] = (_Float16)zfn[j];
      *reinterpret_cast<v4h*>(&zf_h[16 * w + 4 * g]) = zp;
    }
    __syncthreads();   // B2: zf(t+1) visible to all waves
  }

  // ---- final flush (last chunk) ----
  {
    const int c0 = T - CHUNK;
    #pragma unroll
    for (int k = 0; k < 4; ++k) {
      const int flat = k * 2048 + tid * 4;
      const float4 v = *reinterpret_cast<const float4*>(&((float*)outc)[flat]);
      *reinterpret_cast<float4*>(out + ((size_t)b * T + c0) * DX + flat) = v;
    }
  }
}

extern "C" void kernel_launch(void* const* d_in, const int* in_sizes, int n_in,
                              void* d_out, int out_size, void* d_ws, size_t ws_size,
                              hipStream_t stream) {
  const float* X  = (const float*)d_in[0];
  const float* S  = (const float*)d_in[1];
  const float* A  = (const float*)d_in[2];
  const float* W1 = (const float*)d_in[3];
  const float* W2 = (const float*)d_in[4];
  const float* h1 = (const float*)d_in[5];
  const float* h2 = (const float*)d_in[6];
  const float* C  = (const float*)d_in[7];
  float* out = (float*)d_out;
  plrnn_kernel<<<dim3(NB), dim3(512), 0, stream>>>(X, S, A, W1, W2, h1, h2, C, out);
}